// Round 1
// baseline (300.992 us; speedup 1.0000x reference)
//
#include <hip/hip_runtime.h>

// DepthDeformConvPack on MI355X — round 5: de-latency-ify K3.
// r4 post-mortem: FETCH fixed (15.8MB) but MfmaUtil 5.7%, VALUBusy 20%,
// Occupancy 21% -> latency-bound. Grid 256 = 1 block/CU (25% occ ceiling),
// and VGPR=52 proves the compiler serialized sample()'s per-value
// ds_read->global->fma chain instead of pipelining it. Changes:
//   (a) BN 64->32 px, grid 512 = 2 blocks/CU (16 waves/CU). px-split needs
//       no reduction (unlike split-K). XCD swizzle kept: b&7 = XCD, the two
//       co-resident blocks share the same ~2.4MB L2 strip.
//   (b) sample split into issue (all LDS param reads, then all 8 global
//       loads, before the MFMA block) + finish (cvt + one ds_write_b64,
//       after the MFMA block) with explicit register arrays;
//       __launch_bounds__(512,4) caps VGPR at 128 (est. ~100 live).
//   (c) LDS patterns re-derived for BN=32: b64 B-write, b128 B-frag read,
//       pwT/piT reads all at the 64-lane/32-bank minimum.

typedef __bf16 bf16x8 __attribute__((ext_vector_type(8)));
typedef float f32x4 __attribute__((ext_vector_type(4)));
typedef float float2_u __attribute__((ext_vector_type(2), aligned(4)));

__device__ __forceinline__ unsigned short f2bf(float f) {
  unsigned b = __float_as_uint(f);
  return (unsigned short)((b + 0x7fffu + ((b >> 16) & 1u)) >> 16);
}

// ---------------------------------------------------------------------------
// K0: weight fp32 -> bf16, natural layout (k = c*9+tap is already channel-major)
// ---------------------------------------------------------------------------
__global__ __launch_bounds__(256) void k_prep_weight(
    const float* __restrict__ w, unsigned short* __restrict__ wbf)
{
  const int i = blockIdx.x * 256 + threadIdx.x;   // grid 2304 -> 589824
  wbf[i] = f2bf(w[i]);
}

// ---------------------------------------------------------------------------
// K1: offset conv. grid = 4 ch-segments x (n,ho)=256 -> 1024 blocks, 256 thr.
// ---------------------------------------------------------------------------
__global__ __launch_bounds__(256) void k_offset_conv(
    const float* __restrict__ x, const float* __restrict__ depth,
    const float* __restrict__ off_w, const float* __restrict__ off_b,
    float* __restrict__ offs)
{
  const int seg = blockIdx.x >> 8;        // 0..3
  const int nh  = blockIdx.x & 255;
  const int n = nh >> 6, ho = nh & 63;
  const int tid = threadIdx.x;
  const int lane = tid & 63;              // == wo
  const int wave = tid >> 6;

  float acc[18];
#pragma unroll
  for (int i = 0; i < 18; ++i) acc[i] = 0.f;

  const int c0 = __builtin_amdgcn_readfirstlane(seg * 80 + wave * 20);

  for (int ci = 0; ci < 20; ++ci) {
    const int c = c0 + ci;
    const float* p = (c < 256) ? (x + (((n << 8) + c) << 12))
                               : (depth + (((n << 6) + (c - 256)) << 12));
    const float v0 = (ho > 0)  ? p[((ho - 1) << 6) + lane] : 0.f;
    const float v1 =             p[( ho      << 6) + lane];
    const float v2 = (ho < 63) ? p[((ho + 1) << 6) + lane] : 0.f;

    float v[9];
#pragma unroll
    for (int ky = 0; ky < 3; ++ky) {
      const float r = (ky == 0) ? v0 : ((ky == 1) ? v1 : v2);
#pragma unroll
      for (int kx = 0; kx < 3; ++kx) {
        const int src = lane + kx - 1;
        const float s = __shfl(r, src & 63);
        v[ky * 3 + kx] = (src >= 0 && src < 64) ? s : 0.f;
      }
    }
    const float* wp = off_w + c * 9;   // wave-uniform address
#pragma unroll
    for (int co = 0; co < 18; ++co) {
      const float* w = wp + co * 2880;
#pragma unroll
      for (int t = 0; t < 9; ++t) acc[co] += v[t] * w[t];
    }
  }

  __shared__ float red[4][18][64];
#pragma unroll
  for (int co = 0; co < 18; ++co) red[wave][co][lane] = acc[co];
  __syncthreads();
  for (int o = tid; o < 18 * 64; o += 256) {
    const int co = o >> 6, wo = o & 63;
    float s = red[0][co][wo] + red[1][co][wo] + red[2][co][wo] + red[3][co][wo];
    if (seg == 0) s += off_b[co];
    atomicAdd(&offs[((n * 18 + co) << 12) + (ho << 6) + wo], s);
  }
}

// ---------------------------------------------------------------------------
// K2: mask deform conv on depth + sigmoid. 256 blocks (n,ho), 512 thr = 8 waves.
// ---------------------------------------------------------------------------
__global__ __launch_bounds__(512) void k_mask_conv(
    const float* __restrict__ depth, const float* __restrict__ offs,
    const float* __restrict__ mask_w, const float* __restrict__ mask_b,
    float* __restrict__ mask)
{
  const int n  = blockIdx.x >> 6;
  const int ho = blockIdx.x & 63;
  const int tid  = threadIdx.x;
  const int lane = tid & 63;          // wo
  const int wave = tid >> 6;          // 0..7
  const int wo = lane;

  int i00[9], i01[9], i10[9], i11[9];
  float cw00[9], cw01[9], cw10[9], cw11[9];
  const float* op = offs + ((n * 18) << 12) + (ho << 6) + wo;
#pragma unroll
  for (int k = 0; k < 9; ++k) {
    const float dy = op[(2 * k) << 12];
    const float dx = op[(2 * k + 1) << 12];
    const float yy = (float)(ho - 1 + k / 3) + dy;
    const float xx = (float)(wo - 1 + k % 3) + dx;
    const float y0f = floorf(yy), x0f = floorf(xx);
    const float ly = yy - y0f, lx = xx - x0f;
    const int y0 = (int)y0f, x0 = (int)x0f;
    const int y0c = min(max(y0, 0), 63),     x0c = min(max(x0, 0), 63);
    const int y1c = min(max(y0 + 1, 0), 63), x1c = min(max(x0 + 1, 0), 63);
    const float fy0 = (y0 >= 0 && y0 < 64) ? 1.f : 0.f;
    const float fy1 = (y0 >= -1 && y0 < 63) ? 1.f : 0.f;
    const float fx0 = (x0 >= 0 && x0 < 64) ? 1.f : 0.f;
    const float fx1 = (x0 >= -1 && x0 < 63) ? 1.f : 0.f;
    i00[k] = (y0c << 6) + x0c;  i01[k] = (y0c << 6) + x1c;
    i10[k] = (y1c << 6) + x0c;  i11[k] = (y1c << 6) + x1c;
    cw00[k] = (1.f - ly) * (1.f - lx) * fy0 * fx0;
    cw01[k] = (1.f - ly) * lx * fy0 * fx1;
    cw10[k] = ly * (1.f - lx) * fy1 * fx0;
    cw11[k] = ly * lx * fy1 * fx1;
  }

  float acc[9];
#pragma unroll
  for (int i = 0; i < 9; ++i) acc[i] = 0.f;

  const int cbase = __builtin_amdgcn_readfirstlane(wave * 8);
  for (int cc = 0; cc < 8; ++cc) {
    const int c = cbase + cc;
    const float* p = depth + (((n << 6) + c) << 12);
    float val[9];
#pragma unroll
    for (int k = 0; k < 9; ++k) {
      val[k] = p[i00[k]] * cw00[k] + p[i01[k]] * cw01[k] +
               p[i10[k]] * cw10[k] + p[i11[k]] * cw11[k];
    }
    const float* wp = mask_w + c * 9;
#pragma unroll
    for (int co = 0; co < 9; ++co) {
#pragma unroll
      for (int k = 0; k < 9; ++k) acc[co] += val[k] * wp[co * 576 + k];
    }
  }

  __shared__ float red[8][9][64];
#pragma unroll
  for (int co = 0; co < 9; ++co) red[wave][co][lane] = acc[co];
  __syncthreads();
  for (int o = tid; o < 9 * 64; o += 512) {
    const int co = o >> 6, w2 = o & 63;
    float s = mask_b[co];
#pragma unroll
    for (int w = 0; w < 8; ++w) s += red[w][co][w2];
    mask[((n * 9 + co) << 12) + (ho << 6) + w2] = 1.f / (1.f + expf(-s));
  }
}

// ---------------------------------------------------------------------------
// K3: main modulated deform conv, bf16 MFMA GEMM, channel-major K.
// C[256co x 16384px] = Wbf[256 x 2304] * cols[2304 x px], k = c*9 + tap.
// Block: BN=32 px (half an output row), BM=256, BK=64, 512 thr = 8 waves.
// grid 512 -> 2 blocks/CU (16 waves/CU). Sample pipelined: issue (LDS params
// then 8 global loads) before the MFMA block, finish (cvt + ds_write) after.
// ---------------------------------------------------------------------------
__global__ __launch_bounds__(512, 4) void k_deform_gemm(
    const float* __restrict__ x, const float* __restrict__ offs,
    const float* __restrict__ mask, const unsigned short* __restrict__ wbf,
    const float* __restrict__ bias, float* __restrict__ out)
{
  __shared__ __align__(16) unsigned short Bs[2][32][72];  // 9216 B
  __shared__ float4 pwT[9][32];   // [tap][px] remapped weights  4608 B
  __shared__ int2   piT[9][32];   // [tap][px] byte offsets      2304 B

  const int tid = threadIdx.x;
  // XCD swizzle: b&7 = XCD; each XCD owns a 32-row strip of one batch.
  const int b    = blockIdx.x;           // 512 blocks
  const int xcd  = b & 7, slot = b >> 3; // slot 0..63
  const int n    = xcd >> 1;
  const int ho   = ((xcd & 1) << 5) + (slot >> 1);   // 0..63
  const int wo0  = (slot & 1) << 5;                  // 0 or 32
  const int pxb  = (ho << 6) + wo0;                  // px base within batch

  // phase 0: sampling params for 32 px x 9 taps
  if (tid < 288) {
    const int tap = tid >> 5, pl = tid & 31;
    const int wo = wo0 + pl;
    const float dy = offs[((n * 18 + 2 * tap) << 12) + (ho << 6) + wo];
    const float dx = offs[((n * 18 + 2 * tap + 1) << 12) + (ho << 6) + wo];
    const float m  = mask[((n * 9 + tap) << 12) + (ho << 6) + wo];
    const float yy = (float)(ho - 1 + tap / 3) + dy;
    const float xx = (float)(wo - 1 + tap % 3) + dx;
    const float y0f = floorf(yy), x0f = floorf(xx);
    const float ly = yy - y0f, lx = xx - x0f;
    const int y0 = (int)y0f, x0 = (int)x0f;
    const int y0c = min(max(y0, 0), 63);
    const int y1c = min(max(y0 + 1, 0), 63);
    const float fy0 = (y0 >= 0 && y0 < 64) ? 1.f : 0.f;
    const float fy1 = (y0 >= -1 && y0 < 63) ? 1.f : 0.f;
    // horizontal pair remap: contribution = wl*p[bx] + wr*p[bx+1], all
    // clamp/validity cases folded (bx<=62 -> pair never crosses the row).
    const int x0c = min(max(x0, 0), 63);
    const int x1c = min(max(x0 + 1, 0), 63);
    const int bx  = min(max(x0, 0), 62);
    const float vx0 = (x0 >= 0 && x0 < 64) ? 1.f : 0.f;
    const float vx1 = (x0 >= -1 && x0 < 63) ? 1.f : 0.f;
    const float wl = (1.f - lx) * vx0 * ((x0c == bx) ? 1.f : 0.f)
                   + lx * vx1 * ((x1c == bx) ? 1.f : 0.f);
    const float wr = (1.f - lx) * vx0 * ((x0c == bx + 1) ? 1.f : 0.f)
                   + lx * vx1 * ((x1c == bx + 1) ? 1.f : 0.f);
    const float a0 = (1.f - ly) * fy0 * m;
    const float a1 = ly * fy1 * m;
    pwT[tap][pl] = make_float4(wl * a0, wr * a0, wl * a1, wr * a1);
    piT[tap][pl] = make_int2((((y0c << 6) + bx) << 2), (((y1c << 6) + bx) << 2));
  }
  __syncthreads();

  const int pxl  = tid & 31;        // px within block
  const int kq   = tid >> 5;        // 0..15 -> k-quad of 4
  const int wv   = tid >> 6;        // wave 0..7
  const int lane = tid & 63;
  const int mrow = lane & 15;
  const int koct = lane >> 4;       // 0..3 -> k-subgroup of 8
  const float* xn = x + ((long)(n << 8) << 12);

  // sample pipeline state (explicit arrays, static indices -> registers)
  float4   w_[4];
  float2_u pa_[4], pb_[4];

  auto issue = [&](int kc) {
    const int k0 = kc + (kq << 2);                  // first k of this quad
    int c = (int)(((unsigned)k0 * 7282u) >> 16);    // k0/9 (magic, k<2304)
    int tt = k0 - 9 * c;
    int2 ii[4];
    const char* pp[4];
    const char* p = (const char*)(xn + (c << 12));
#pragma unroll
    for (int j = 0; j < 4; ++j) {                   // phase A: LDS param reads
      w_[j] = pwT[tt][pxl];
      ii[j] = piT[tt][pxl];
      pp[j] = p;
      if (++tt == 9) { tt = 0; p += 16384; }        // next channel image
    }
#pragma unroll
    for (int j = 0; j < 4; ++j) {                   // phase B: 8 global loads
      pa_[j] = *(const float2_u*)(pp[j] + ii[j].x);
      pb_[j] = *(const float2_u*)(pp[j] + ii[j].y);
    }
  };
  auto finish = [&](int buf) {                      // phase C: cvt + LDS write
    __align__(8) unsigned short v[4];
#pragma unroll
    for (int j = 0; j < 4; ++j)
      v[j] = f2bf(pa_[j].x * w_[j].x + pa_[j].y * w_[j].y +
                  pb_[j].x * w_[j].z + pb_[j].y * w_[j].w);
    *(int2*)&Bs[buf][pxl][kq << 2] = *(const int2*)v;
  };

  f32x4 acc[2][2];
#pragma unroll
  for (int mt = 0; mt < 2; ++mt)
#pragma unroll
    for (int nt = 0; nt < 2; ++nt)
#pragma unroll
      for (int r = 0; r < 4; ++r) acc[mt][nt][r] = 0.f;

  issue(0);
  finish(0);
  __syncthreads();

  for (int ic = 0; ic < 36; ++ic) {
    const int kc = ic << 6;
    // A fragments for this iter (global, L2-hot)
    bf16x8 af[2][2];
#pragma unroll
    for (int mt = 0; mt < 2; ++mt)
#pragma unroll
      for (int ks = 0; ks < 2; ++ks) {
        const int row = (wv << 5) + (mt << 4) + mrow;
        const int col = kc + (ks << 5) + (koct << 3);
        af[mt][ks] = *(const bf16x8*)(wbf + row * 2304 + col);
      }

    if (ic + 1 < 36) issue((ic + 1) << 6);   // loads in flight across MFMAs

    const int buf = ic & 1;
#pragma unroll
    for (int ks = 0; ks < 2; ++ks)
#pragma unroll
      for (int nt = 0; nt < 2; ++nt) {
        const bf16x8 bfr =
            *(const bf16x8*)&Bs[buf][(nt << 4) + mrow][(ks << 5) + (koct << 3)];
        acc[0][nt] = __builtin_amdgcn_mfma_f32_16x16x32_bf16(af[0][ks], bfr,
                                                             acc[0][nt], 0, 0, 0);
        acc[1][nt] = __builtin_amdgcn_mfma_f32_16x16x32_bf16(af[1][ks], bfr,
                                                             acc[1][nt], 0, 0, 0);
      }

    if (ic + 1 < 36) finish((ic + 1) & 1);   // write-late into the other buf
    __syncthreads();
  }

  // epilogue: C/D layout col=lane&15 (px), row=(lane>>4)*4+r (co)
#pragma unroll
  for (int mt = 0; mt < 2; ++mt)
#pragma unroll
    for (int nt = 0; nt < 2; ++nt)
#pragma unroll
      for (int r = 0; r < 4; ++r) {
        const int co = (wv << 5) + (mt << 4) + ((lane >> 4) << 2) + r;
        const int pxg = pxb + (nt << 4) + (lane & 15);
        out[(((n << 8) + co) << 12) + pxg] = acc[mt][nt][r] + bias[co];
      }
}

// ---------------------------------------------------------------------------
extern "C" void kernel_launch(void* const* d_in, const int* in_sizes, int n_in,
                              void* d_out, int out_size, void* d_ws, size_t ws_size,
                              hipStream_t stream) {
  const float* x      = (const float*)d_in[0];
  const float* depth  = (const float*)d_in[1];
  const float* weight = (const float*)d_in[2];
  const float* bias   = (const float*)d_in[3];
  const float* off_w  = (const float*)d_in[4];
  const float* off_b  = (const float*)d_in[5];
  const float* mask_w = (const float*)d_in[6];
  const float* mask_b = (const float*)d_in[7];
  float* out = (float*)d_out;

  float* offs = (float*)d_ws;                       // 294912 floats
  float* mask = offs + 294912;                      // 147456 floats
  unsigned short* wbf = (unsigned short*)(mask + 147456);  // 589824 bf16

  hipMemsetAsync(offs, 0, 294912 * sizeof(float), stream);
  k_prep_weight<<<2304, 256, 0, stream>>>(weight, wbf);
  k_offset_conv<<<1024, 256, 0, stream>>>(x, depth, off_w, off_b, offs);
  k_mask_conv<<<256, 512, 0, stream>>>(depth, offs, mask_w, mask_b, mask);
  k_deform_gemm<<<512, 512, 0, stream>>>(x, offs, mask, wbf, bias, out);
}